// Round 1
// 331.012 us; speedup vs baseline: 1.4202x; 1.4202x over previous
//
#include <hip/hip_runtime.h>
#include <math.h>

typedef unsigned short u16;
typedef unsigned int u32;

// Problem constants
#define NPTS 16384
#define HID  512
#define TT   8
#define TE   64
#define NB   16
#define OUTC 218

__device__ __forceinline__ float bf2f(u16 u) {
  return __uint_as_float(((u32)u) << 16);
}
__device__ __forceinline__ u16 f2bf(float f) {
  u32 x = __float_as_uint(f);
  x += 0x7fffu + ((x >> 16) & 1u);
  return (u16)(x >> 16);
}
__device__ __forceinline__ float lrelu(float h) { return fmaxf(h, 0.02f * h); }

// dtype-adaptive external tensor access (f32 flag sniffed at runtime)
__device__ __forceinline__ float rd(const void* p, size_t i, bool f32) {
  return f32 ? ((const float*)p)[i] : bf2f(((const u16*)p)[i]);
}
__device__ __forceinline__ void wr(void* p, size_t i, bool f32, float v) {
  if (f32) ((float*)p)[i] = v;
  else ((u16*)p)[i] = f2bf(v);
}

// ---------------------------------------------------------------------------
// Sniff: if inputs are fp32 read as bf16 pairs, the low halves are mantissa
// bits -> ~1/256 of them match the bf16 Inf/NaN exponent pattern. Finite bf16
// inputs can never match. flag=1 -> fp32 world, flag=0 -> bf16 world.
// ---------------------------------------------------------------------------
__global__ __launch_bounds__(256) void sniff_kernel(const u16* __restrict__ pe,
                                                    int* __restrict__ flag) {
  __shared__ int s;
  const int tid = threadIdx.x;
  if (tid == 0) s = 0;
  __syncthreads();
  int c = 0;
  for (int i = tid; i < 8192; i += 256) {
    const u16 v = pe[i];
    if ((v & 0x7F80u) == 0x7F80u) c = 1;
  }
  if (c) s = 1;  // benign race, same value
  __syncthreads();
  if (tid == 0) flag[0] = s;
}

// ---------------------------------------------------------------------------
// Prep: blocks 0..7 : vprime[t][j] = hm_b1[j] + sum_e traj[t,e]*hm_w1[512+e][j]
//       blocks 8..15: avp[t][j]    = ab1[j]   + sum_e traj[t,e]*aw1[512+e][j]
//       block  16   : w2f (2048) + b2f (4) -> fp32
// ---------------------------------------------------------------------------
__global__ __launch_bounds__(256) void prep_kernel(
    const void* __restrict__ hm_w1, const void* __restrict__ hm_b1,
    const void* __restrict__ traj, const void* __restrict__ hm_w2,
    const void* __restrict__ hm_b2, const void* __restrict__ aw1,
    const void* __restrict__ ab1, float* __restrict__ vprime,
    float* __restrict__ w2f, float* __restrict__ b2f,
    float* __restrict__ avp, const int* __restrict__ flag) {
  const bool f32 = flag[0] != 0;
  const int tid = threadIdx.x, blk = blockIdx.x;
  if (blk < 8) {
    const int t = blk;
    for (int j = tid; j < 512; j += 256) {
      float acc = rd(hm_b1, j, f32);
      for (int e = 0; e < 64; ++e)
        acc = fmaf(rd(traj, t * 64 + e, f32),
                   rd(hm_w1, (size_t)(512 + e) * 512 + j, f32), acc);
      vprime[t * 512 + j] = acc;
    }
  } else if (blk < 16) {
    const int t = blk - 8;
    for (int j = tid; j < 512; j += 256) {
      float acc = rd(ab1, j, f32);
      for (int e = 0; e < 64; ++e)
        acc = fmaf(rd(traj, t * 64 + e, f32),
                   rd(aw1, (size_t)(512 + e) * 512 + j, f32), acc);
      avp[t * 512 + j] = acc;
    }
  } else {
    for (int i = tid; i < 2048; i += 256) w2f[i] = rd(hm_w2, i, f32);
    if (tid < 4) b2f[tid] = rd(hm_b2, tid, f32);
  }
}

// ---------------------------------------------------------------------------
// VALU GEMM (no MFMA): U[n][j] = sum_k pe[n][k]*hm_w1[k][j].
// Block = 16 rows; A rows staged to LDS fp32 (reads are wave-broadcast, so
// ds cost is small); thread tid covers cols tid, tid+256 (coalesced W1 row
// reads). fp32 accumulate. 16 rows doubles FMA per staged-W load vs 8.
// ---------------------------------------------------------------------------
#define GR 16
#define KBODY                                                                  \
  _Pragma("unroll") for (int r = 0; r < GR; ++r) {                             \
    const float4 a = *(const float4*)&sA[r * 512 + k];                         \
    acc0[r] = fmaf(a.x, w0[0],                                                 \
              fmaf(a.y, w0[1], fmaf(a.z, w0[2], fmaf(a.w, w0[3], acc0[r])))); \
    acc1[r] = fmaf(a.x, w1[0],                                                 \
              fmaf(a.y, w1[1], fmaf(a.z, w1[2], fmaf(a.w, w1[3], acc1[r])))); \
  }

__global__ __launch_bounds__(256) void gemm_naive(
    const void* __restrict__ A, const void* __restrict__ W1,
    float* __restrict__ U, const int* __restrict__ flag) {
  const bool f32 = flag[0] != 0;
  __shared__ float sA[GR * 512];
  const int tid = threadIdx.x;
  const int rb = blockIdx.x * GR;
  for (int i = tid; i < GR * 512; i += 256) {
    const int r = i >> 9, k = i & 511;
    sA[i] = rd(A, (size_t)(rb + r) * 512 + k, f32);
  }
  __syncthreads();
  const int j0 = tid, j1 = tid + 256;
  float acc0[GR], acc1[GR];
#pragma unroll
  for (int r = 0; r < GR; ++r) { acc0[r] = 0.f; acc1[r] = 0.f; }
  if (f32) {
    const float* W = (const float*)W1;
    for (int k = 0; k < 512; k += 4) {
      float w0[4], w1[4];
#pragma unroll
      for (int kk = 0; kk < 4; ++kk) {
        w0[kk] = W[(size_t)(k + kk) * 512 + j0];
        w1[kk] = W[(size_t)(k + kk) * 512 + j1];
      }
      KBODY
    }
  } else {
    const u16* W = (const u16*)W1;
    for (int k = 0; k < 512; k += 4) {
      float w0[4], w1[4];
#pragma unroll
      for (int kk = 0; kk < 4; ++kk) {
        w0[kk] = bf2f(W[(size_t)(k + kk) * 512 + j0]);
        w1[kk] = bf2f(W[(size_t)(k + kk) * 512 + j1]);
      }
      KBODY
    }
  }
#pragma unroll
  for (int r = 0; r < GR; ++r) {
    U[(size_t)(rb + r) * 512 + j0] = acc0[r];
    U[(size_t)(rb + r) * 512 + j1] = acc1[r];
  }
}

// ---------------------------------------------------------------------------
// Segment-max partials: block = (b, chunk c of 16). partial[(b*16+c)*512+j].
// ---------------------------------------------------------------------------
__global__ __launch_bounds__(256) void segmax_kernel(
    const void* __restrict__ pe, const int* __restrict__ npts,
    float* __restrict__ partial, const int* __restrict__ flag) {
  const bool f32 = flag[0] != 0;
  const int blk = blockIdx.x;
  const int b = blk >> 4, c = blk & 15;
  int s0 = 0, cnt = 0;
  for (int i = 0; i < 16; ++i) {
    const int v = npts[i];
    if (i < b) s0 += v;
    if (i == b) cnt = v;
  }
  const int chunk = (cnt + 15) >> 4;
  const int r0 = s0 + c * chunk;
  int r1 = r0 + chunk;
  const int rend = s0 + cnt;
  if (r1 > rend) r1 = rend;
  const int j2 = threadIdx.x;  // covers cols 2*j2, 2*j2+1
  float m0 = -1e30f, m1 = -1e30f;
  if (f32) {
    const float* pf = (const float*)pe;
    for (int n = r0; n < r1; ++n) {
      const float2 v = *(const float2*)(pf + (size_t)n * 512 + 2 * j2);
      m0 = fmaxf(m0, v.x);
      m1 = fmaxf(m1, v.y);
    }
  } else {
    const u32* p32 = (const u32*)pe;
    for (int n = r0; n < r1; ++n) {
      const u32 v = p32[(size_t)n * 256 + j2];
      m0 = fmaxf(m0, bf2f((u16)(v & 0xffffu)));
      m1 = fmaxf(m1, bf2f((u16)(v >> 16)));
    }
  }
  partial[(size_t)blk * 512 + 2 * j2] = m0;
  partial[(size_t)blk * 512 + 2 * j2 + 1] = m1;
}

// ---------------------------------------------------------------------------
// Stage 2: per (n,t): hm = lrelu(u[n]+v'[t]) @ w2 + b2 -> logits, new_coords.
// ---------------------------------------------------------------------------
__global__ __launch_bounds__(256) void stage2_kernel(
    const float* __restrict__ U, const float* __restrict__ vprime,
    const float* __restrict__ w2f, const float* __restrict__ b2f,
    const void* __restrict__ coords, float* __restrict__ logits,
    float* __restrict__ nc, const int* __restrict__ flag) {
  const bool f32 = flag[0] != 0;
  __shared__ float s_vp[TT * 512];
  const int tid = threadIdx.x;
  for (int i = tid; i < TT * 512; i += 256) s_vp[i] = vprime[i];
  __syncthreads();
  const int g = (blockIdx.x << 8) + tid;  // (n, t), t fast
  const int n = g >> 3, t = g & 7;
  const float4* u4 = (const float4*)(U + (size_t)n * 512);
  const float4* v4 = (const float4*)(s_vp + t * 512);
  const float4* w4 = (const float4*)w2f;
  float a0 = 0.f, a1 = 0.f, a2 = 0.f, a3 = 0.f;
  for (int j4 = 0; j4 < 128; ++j4) {
    const float4 uu = u4[j4];
    const float4 vv = v4[j4];
    const float4 w_0 = w4[j4 * 4 + 0];
    const float4 w_1 = w4[j4 * 4 + 1];
    const float4 w_2 = w4[j4 * 4 + 2];
    const float4 w_3 = w4[j4 * 4 + 3];
    float h;
    h = lrelu(uu.x + vv.x);
    a0 = fmaf(h, w_0.x, a0); a1 = fmaf(h, w_0.y, a1);
    a2 = fmaf(h, w_0.z, a2); a3 = fmaf(h, w_0.w, a3);
    h = lrelu(uu.y + vv.y);
    a0 = fmaf(h, w_1.x, a0); a1 = fmaf(h, w_1.y, a1);
    a2 = fmaf(h, w_1.z, a2); a3 = fmaf(h, w_1.w, a3);
    h = lrelu(uu.z + vv.z);
    a0 = fmaf(h, w_2.x, a0); a1 = fmaf(h, w_2.y, a1);
    a2 = fmaf(h, w_2.z, a2); a3 = fmaf(h, w_2.w, a3);
    h = lrelu(uu.w + vv.w);
    a0 = fmaf(h, w_3.x, a0); a1 = fmaf(h, w_3.y, a1);
    a2 = fmaf(h, w_3.z, a2); a3 = fmaf(h, w_3.w, a3);
  }
  logits[g] = a0 + b2f[0];
  float* o = nc + (size_t)g * 3;
  o[0] = rd(coords, (size_t)n * 3 + 0, f32) + a1 + b2f[1];
  o[1] = rd(coords, (size_t)n * 3 + 1, f32) + a2 + b2f[2];
  o[2] = rd(coords, (size_t)n * 3 + 2, f32) + a3 + b2f[3];
}

// ---------------------------------------------------------------------------
// Per-segment softmax + weighted coord sum -> xt (out offset 0).
// ---------------------------------------------------------------------------
__global__ __launch_bounds__(256) void softmax_xt_kernel(
    const float* __restrict__ logits, const float* __restrict__ nc,
    const int* __restrict__ npts, void* __restrict__ out,
    const int* __restrict__ flag) {
  const bool f32 = flag[0] != 0;
  const int b = blockIdx.x, tid = threadIdx.x;
  int s0 = 0, cnt = 0;
  for (int i = 0; i < 16; ++i) {
    const int v = npts[i];
    if (i < b) s0 += v;
    if (i == b) cnt = v;
  }
  const int base = s0 * 8, total = cnt * 8;
  const int t = tid & 7, grp = tid >> 3;
  __shared__ float sm[8][32];
  __shared__ float mf[8];
  __shared__ float s4[4][8][32];
  float m = -1e30f;
  for (int idx = tid; idx < total; idx += 256)
    m = fmaxf(m, logits[base + idx]);
  sm[t][grp] = m;
  __syncthreads();
  if (tid < 8) {
    float mm = -1e30f;
    for (int i = 0; i < 32; ++i) mm = fmaxf(mm, sm[tid][i]);
    mf[tid] = mm;
  }
  __syncthreads();
  const float mt = mf[t];
  float z = 0.f, x = 0.f, y = 0.f, ww = 0.f;
  for (int idx = tid; idx < total; idx += 256) {
    const float e = expf(logits[base + idx] - mt);
    const float* c3 = nc + (size_t)(base + idx) * 3;
    z += e;
    x = fmaf(e, c3[0], x);
    y = fmaf(e, c3[1], y);
    ww = fmaf(e, c3[2], ww);
  }
  s4[0][t][grp] = z; s4[1][t][grp] = x; s4[2][t][grp] = y; s4[3][t][grp] = ww;
  __syncthreads();
  if (tid < 8) {
    float Z = 0.f, X = 0.f, Y = 0.f, W = 0.f;
    for (int i = 0; i < 32; ++i) {
      Z += s4[0][tid][i]; X += s4[1][tid][i];
      Y += s4[2][tid][i]; W += s4[3][tid][i];
    }
    wr(out, (size_t)(b * 8 + tid) * 3 + 0, f32, X / Z);
    wr(out, (size_t)(b * 8 + tid) * 3 + 1, f32, Y / Z);
    wr(out, (size_t)(b * 8 + tid) * 3 + 2, f32, W / Z);
  }
}

// ---------------------------------------------------------------------------
// act_hid: exploit concat structure of the action MLP input.
//   hid[b][t][j] = lrelu( sum_k pc[b][k]*aw1[k][j] + avp[t][j] )
// Unique GEMM is only (16 x 512) @ (512 x 512). Grid = 16 b x 8 jtiles of 64.
// Threads: jj = tid&63 (column within tile), kq = tid>>6 (k-chunk of 128).
// aw1 reads coalesced across jj; pc broadcast from LDS; 4-chunk LDS reduce.
// ---------------------------------------------------------------------------
__global__ __launch_bounds__(256) void act_hid_kernel(
    const float* __restrict__ partial, const void* __restrict__ aw1,
    const float* __restrict__ avp, float* __restrict__ hid,
    const int* __restrict__ flag) {
  const bool f32 = flag[0] != 0;
  const int b = blockIdx.x >> 3, jt = blockIdx.x & 7;
  __shared__ float spc[512];
  __shared__ float sred[4][64];
  const int tid = threadIdx.x;
  // pc[b][k] = max over 16 chunk-partials (partial is 512KB, L2-resident)
  for (int k = tid; k < 512; k += 256) {
    float m = -1e30f;
#pragma unroll
    for (int c = 0; c < 16; ++c)
      m = fmaxf(m, partial[(size_t)(b * 16 + c) * 512 + k]);
    spc[k] = m;
  }
  __syncthreads();
  const int jj = tid & 63, kq = tid >> 6;
  const int j = jt * 64 + jj;
  const int kb = kq * 128;
  float a0 = 0.f, a1 = 0.f, a2 = 0.f, a3 = 0.f;
  if (f32) {
    const float* W = (const float*)aw1 + (size_t)kb * 512 + j;
#pragma unroll 4
    for (int k = 0; k < 128; k += 4) {
      a0 = fmaf(spc[kb + k + 0], W[(size_t)(k + 0) * 512], a0);
      a1 = fmaf(spc[kb + k + 1], W[(size_t)(k + 1) * 512], a1);
      a2 = fmaf(spc[kb + k + 2], W[(size_t)(k + 2) * 512], a2);
      a3 = fmaf(spc[kb + k + 3], W[(size_t)(k + 3) * 512], a3);
    }
  } else {
    const u16* W = (const u16*)aw1 + (size_t)kb * 512 + j;
#pragma unroll 4
    for (int k = 0; k < 128; k += 4) {
      a0 = fmaf(spc[kb + k + 0], bf2f(W[(size_t)(k + 0) * 512]), a0);
      a1 = fmaf(spc[kb + k + 1], bf2f(W[(size_t)(k + 1) * 512]), a1);
      a2 = fmaf(spc[kb + k + 2], bf2f(W[(size_t)(k + 2) * 512]), a2);
      a3 = fmaf(spc[kb + k + 3], bf2f(W[(size_t)(k + 3) * 512]), a3);
    }
  }
  sred[kq][jj] = (a0 + a1) + (a2 + a3);
  __syncthreads();
  if (kq == 0) {
    const float s = (sred[0][jj] + sred[1][jj]) + (sred[2][jj] + sred[3][jj]);
#pragma unroll
    for (int t = 0; t < 8; ++t)
      hid[(size_t)(b * 8 + t) * 512 + j] = lrelu(s + avp[t * 512 + j]);
  }
}

// ---------------------------------------------------------------------------
// act_out: ae[row][c] = hid[row] . aw2[:,c] + ab2[c].  Grid = 128 rows.
// hid row staged in LDS (broadcast reads); aw2 reads coalesced across c
// (446KB fp32, L2-resident after first blocks). 4-way ILP accumulators.
// ---------------------------------------------------------------------------
__global__ __launch_bounds__(256) void act_out_kernel(
    const float* __restrict__ hid, const void* __restrict__ aw2,
    const void* __restrict__ ab2, void* __restrict__ out,
    const int* __restrict__ flag) {
  const bool f32 = flag[0] != 0;
  __shared__ float sh[512];
  const int row = blockIdx.x, tid = threadIdx.x;
  for (int i = tid; i < 512; i += 256) sh[i] = hid[(size_t)row * 512 + i];
  __syncthreads();
  if (tid < OUTC) {
    float a0 = 0.f, a1 = 0.f, a2 = 0.f, a3 = 0.f;
    if (f32) {
      const float* W = (const float*)aw2 + tid;
#pragma unroll 8
      for (int j = 0; j < 512; j += 4) {
        a0 = fmaf(sh[j + 0], W[(size_t)(j + 0) * OUTC], a0);
        a1 = fmaf(sh[j + 1], W[(size_t)(j + 1) * OUTC], a1);
        a2 = fmaf(sh[j + 2], W[(size_t)(j + 2) * OUTC], a2);
        a3 = fmaf(sh[j + 3], W[(size_t)(j + 3) * OUTC], a3);
      }
    } else {
      const u16* W = (const u16*)aw2 + tid;
#pragma unroll 8
      for (int j = 0; j < 512; j += 4) {
        a0 = fmaf(sh[j + 0], bf2f(W[(size_t)(j + 0) * OUTC]), a0);
        a1 = fmaf(sh[j + 1], bf2f(W[(size_t)(j + 1) * OUTC]), a1);
        a2 = fmaf(sh[j + 2], bf2f(W[(size_t)(j + 2) * OUTC]), a2);
        a3 = fmaf(sh[j + 3], bf2f(W[(size_t)(j + 3) * OUTC]), a3);
      }
    }
    const float o = rd(ab2, tid, f32) + ((a0 + a1) + (a2 + a3));
    if (tid < 216)
      wr(out, 384 + (size_t)row * 216 + tid, f32, o);
    else if (tid == 216)
      wr(out, 384 + 27648 + row, f32, o);
    else
      wr(out, 384 + 27648 + 128 + row, f32, o);
  }
}

// ---------------------------------------------------------------------------
extern "C" void kernel_launch(void* const* d_in, const int* in_sizes, int n_in,
                              void* d_out, int out_size, void* d_ws,
                              size_t ws_size, hipStream_t stream) {
  (void)in_sizes; (void)n_in; (void)out_size; (void)ws_size;
  const void* pe     = d_in[0];
  const void* coords = d_in[1];
  const void* traj   = d_in[2];
  const void* hm_w1  = d_in[3];
  const void* hm_b1  = d_in[4];
  const void* hm_w2  = d_in[5];
  const void* hm_b2  = d_in[6];
  const void* aw1    = d_in[7];
  const void* ab1    = d_in[8];
  const void* aw2    = d_in[9];
  const void* ab2    = d_in[10];
  const int* npts    = (const int*)d_in[11];

  char* ws = (char*)d_ws;
  // first 512KB slot: flag + avp + hid (all fit: 256 + 16K + 256K < 512K)
  int*   flag    = (int*)(ws + 0);
  float* avp     = (float*)(ws + 256);        //    8*512*4 = 16384
  float* hid     = (float*)(ws + 16896);      //  128*512*4 = 262144
  float* U       = (float*)(ws + 524288);     // 16384*512*4 = 33554432
  float* vprime  = (float*)(ws + 34078720);   //    8*512*4 = 16384
  float* w2f     = (float*)(ws + 34095104);   //     2048*4 = 8192
  float* b2f     = (float*)(ws + 34103296);   //        4*4 (pad to 256)
  float* logits  = (float*)(ws + 34103552);   //  16384*8*4 = 524288
  float* nc      = (float*)(ws + 34627840);   // 16384*8*3*4 = 1572864
  float* partial = (float*)(ws + 36200704);   //  16*16*512*4 = 524288

  sniff_kernel<<<1, 256, 0, stream>>>((const u16*)pe, flag);
  prep_kernel<<<17, 256, 0, stream>>>(hm_w1, hm_b1, traj, hm_w2, hm_b2,
                                      aw1, ab1, vprime, w2f, b2f, avp, flag);
  gemm_naive<<<NPTS / GR, 256, 0, stream>>>(pe, hm_w1, U, flag);
  segmax_kernel<<<256, 256, 0, stream>>>(pe, npts, partial, flag);
  stage2_kernel<<<512, 256, 0, stream>>>(U, vprime, w2f, b2f, coords, logits,
                                         nc, flag);
  softmax_xt_kernel<<<16, 256, 0, stream>>>(logits, nc, npts, d_out, flag);
  act_hid_kernel<<<128, 256, 0, stream>>>(partial, aw1, avp, hid, flag);
  act_out_kernel<<<128, 256, 0, stream>>>(hid, aw2, ab2, d_out, flag);
}